// Round 1
// baseline (33039.795 us; speedup 1.0000x reference)
//
#include <hip/hip_runtime.h>
#include <math.h>

#define B_  64
#define S_  2048
#define I_  256
#define H_  512
#define K_  768      // I_ + H_
#define G3  1536     // 3*H_

#define RT  16       // rows per WG
#define JT  4        // h-columns per WG
#define NC  12       // gate columns per WG = 3*JT
#define BLK 192      // RT * NC threads
#define LDA 772      // padded LDS row stride in floats (772%8==0 -> 16B aligned rows; 772%32==4 -> 2-way bank aliasing, free)

// Build Vt[c][k] = column-major-transposed [W; U]: Vt is (1536 x 768), k-contiguous.
__global__ __launch_bounds__(256) void prep_transpose(
    const float* __restrict__ W,   // (256, 1536)
    const float* __restrict__ U,   // (512, 1536)
    float* __restrict__ Vt)        // (1536, 768)
{
    const int c = blockIdx.y;
    const int k = blockIdx.x * 256 + threadIdx.x;
    if (k < K_) {
        float v = (k < I_) ? W[(size_t)k * G3 + c] : U[(size_t)(k - I_) * G3 + c];
        Vt[(size_t)c * K_ + k] = v;
    }
}

// One timestep: gates = [x_t | h_in] @ Vt^T + bias ; activations ; write h.
__global__ __launch_bounds__(BLK) void lstm_step(
    const float* __restrict__ x,      // (B, S, I)
    const float* __restrict__ bias,   // (3H)
    const float* __restrict__ Vt,     // (G3, K_)
    const float* __restrict__ h_in,   // (B, H)
    float* __restrict__ h_out,        // (B, H)
    float* __restrict__ hidden,       // (B, S, H) in d_out
    float* __restrict__ hf,           // (B, H)
    float* __restrict__ cf,           // (B, H)
    int t, int is_last)
{
    __shared__ float Alds[RT * LDA];        // [r][k]: k in [0,256) = x_t, [256,768) = h_in
    __shared__ float gtile[NC][RT + 1];     // per-WG gate values

    const int tid = threadIdx.x;
    const int rq  = blockIdx.x & 3;         // row quarter
    const int jq  = blockIdx.x >> 2;        // j quad, 0..127
    const int r0  = rq * RT;

    // ---- stage x_t rows -> Alds[r][0..255] (float4, coalesced) ----
    for (int f4 = tid; f4 < (RT * I_) / 4; f4 += BLK) {
        const int r  = f4 >> 6;             // 64 float4 per row
        const int kk = (f4 & 63) * 4;
        const float4 v = *(const float4*)(x + (size_t)(r0 + r) * (S_ * I_) + (size_t)t * I_ + kk);
        *(float4*)(Alds + r * LDA + kk) = v;
    }
    // ---- stage h_in rows -> Alds[r][256..767] ----
    for (int f4 = tid; f4 < (RT * H_) / 4; f4 += BLK) {
        const int r  = f4 >> 7;             // 128 float4 per row
        const int jj = (f4 & 127) * 4;
        const float4 v = *(const float4*)(h_in + (size_t)(r0 + r) * H_ + jj);
        *(float4*)(Alds + r * LDA + I_ + jj) = v;
    }
    __syncthreads();

    // ---- each thread: one dot product of length 768 ----
    const int r      = tid & 15;
    const int c      = tid >> 4;            // 0..11
    const int region = c >> 2;              // 0=i, 1=g, 2=o
    const int jl     = c & 3;
    const int j      = jq * JT + jl;        // 0..511
    const int cg     = region * H_ + j;     // global gate column

    const float* __restrict__ wrow = Vt + (size_t)cg * K_;
    const float* __restrict__ arow = Alds + r * LDA;

    float4 acc = make_float4(0.f, 0.f, 0.f, 0.f);   // 4 independent chains to cover FMA latency
    #pragma unroll 4
    for (int k = 0; k < K_; k += 8) {
        const float4 a0 = *(const float4*)(arow + k);
        const float4 a1 = *(const float4*)(arow + k + 4);
        const float4 w0 = *(const float4*)(wrow + k);
        const float4 w1 = *(const float4*)(wrow + k + 4);
        acc.x += a0.x * w0.x;  acc.y += a0.y * w0.y;
        acc.z += a0.z * w0.z;  acc.w += a0.w * w0.w;
        acc.x += a1.x * w1.x;  acc.y += a1.y * w1.y;
        acc.z += a1.z * w1.z;  acc.w += a1.w * w1.w;
    }
    gtile[c][r] = (acc.x + acc.y) + (acc.z + acc.w) + bias[cg];
    __syncthreads();

    // ---- activations + stores: 64 threads, one (r, j) each ----
    if (tid < RT * JT) {
        const int rr = tid & 15;
        const int jj = tid >> 4;            // 0..3
        const float gi = gtile[0 * JT + jj][rr];
        const float gg = gtile[1 * JT + jj][rr];
        const float go = gtile[2 * JT + jj][rr];
        const float it = 1.f / (1.f + __expf(-gi));
        const float gt = tanhf(gg);
        const float ot = 1.f / (1.f + __expf(-go));
        const float ct = it * gt;
        const float ht = ot * tanhf(ct);
        const int rg = r0 + rr;
        const int jg = jq * JT + jj;
        h_out[(size_t)rg * H_ + jg] = ht;
        hidden[(size_t)rg * (S_ * H_) + (size_t)t * H_ + jg] = ht;
        if (is_last) {
            hf[(size_t)rg * H_ + jg] = ht;
            cf[(size_t)rg * H_ + jg] = ct;
        }
    }
}

extern "C" void kernel_launch(void* const* d_in, const int* in_sizes, int n_in,
                              void* d_out, int out_size, void* d_ws, size_t ws_size,
                              hipStream_t stream) {
    const float* x    = (const float*)d_in[0];
    const float* W    = (const float*)d_in[1];
    const float* U    = (const float*)d_in[2];
    const float* bias = (const float*)d_in[3];

    float* out    = (float*)d_out;
    float* hidden = out;                                   // B*S*H
    float* hf     = out + (size_t)B_ * S_ * H_;
    float* cf     = hf + (size_t)B_ * H_;

    // workspace layout: Vt (1536*768 f32 = 4.72 MB) | h ping | h pong
    float* Vt = (float*)d_ws;
    float* h0 = Vt + (size_t)G3 * K_;
    float* h1 = h0 + (size_t)B_ * H_;

    // build transposed weights + zero h0 (ws is poisoned every call)
    hipLaunchKernelGGL(prep_transpose, dim3(3, G3), dim3(256), 0, stream, W, U, Vt);
    hipMemsetAsync(h0, 0, (size_t)B_ * H_ * sizeof(float), stream);

    float* hin = h0;
    float* hout = h1;
    for (int t = 0; t < S_; ++t) {
        hipLaunchKernelGGL(lstm_step, dim3(512), dim3(BLK), 0, stream,
                           x, bias, Vt, hin, hout, hidden, hf, cf, t, (t == S_ - 1) ? 1 : 0);
        float* tmp = hin; hin = hout; hout = tmp;
    }
}